// Round 1
// baseline (855.552 us; speedup 1.0000x reference)
//
#include <hip/hip_runtime.h>
#include <math.h>

// GCN 2-layer, N=100000 nodes, E=3200000 edges, feats 2 -> 16 -> 2.
// Key identity: Agg(x @ W) = Agg(x) @ W  (aggregation is linear over nodes),
// so both scatter passes move only 2 floats/edge.
// norm factoring: out[d] = dinv[d] * ( sum_{src->d} dinv[src]*h[src] + dinv[d]*h[d] )

constexpr int N = 100000;

__global__ void k_deg(const int* __restrict__ dst, int E, int* __restrict__ cnt) {
    int e = blockIdx.x * blockDim.x + threadIdx.x;
    if (e < E) atomicAdd(&cnt[dst[e]], 1);
}

// dinv = rsqrt(deg) with deg = cnt + 1 (self loop); sx = x*dinv; agg1 init = sx (self-loop term)
__global__ void k_node1(const float* __restrict__ x, const int* __restrict__ cnt,
                        float* __restrict__ dinv, float2* __restrict__ sx,
                        float2* __restrict__ agg1) {
    int i = blockIdx.x * blockDim.x + threadIdx.x;
    if (i < N) {
        float di = rsqrtf((float)(cnt[i] + 1));
        dinv[i] = di;
        float2 xv = ((const float2*)x)[i];
        float2 s = make_float2(xv.x * di, xv.y * di);
        sx[i] = s;
        agg1[i] = s;
    }
}

__global__ void k_scatter(const int* __restrict__ src, const int* __restrict__ dst, int E,
                          const float2* __restrict__ val, float* __restrict__ agg) {
    int e = blockIdx.x * blockDim.x + threadIdx.x;
    if (e < E) {
        int s = src[e];
        int d = dst[e];
        float2 v = val[s];
        atomicAdd(&agg[2 * d + 0], v.x);
        atomicAdd(&agg[2 * d + 1], v.y);
    }
}

// a = agg1*dinv (= layer1 aggregated x);  h = relu(a@W1 + b1);  z = h@W2;
// sz = z*dinv; agg2 init = sz (self-loop term)
__global__ void k_node2(const float2* __restrict__ agg1, const float* __restrict__ dinv,
                        const float* __restrict__ W1, const float* __restrict__ b1,
                        const float* __restrict__ W2,
                        float2* __restrict__ sz, float2* __restrict__ agg2) {
    __shared__ float sW1[32];  // W1 is (2,16) row-major
    __shared__ float sb1[16];
    __shared__ float sW2[32];  // W2 is (16,2) row-major
    int t = threadIdx.x;
    if (t < 32) sW1[t] = W1[t];
    else if (t < 48) sb1[t - 32] = b1[t - 32];
    else if (t < 80) sW2[t - 48] = W2[t - 48];
    __syncthreads();
    int i = blockIdx.x * blockDim.x + threadIdx.x;
    if (i < N) {
        float di = dinv[i];
        float2 a = agg1[i];
        float a0 = a.x * di;
        float a1 = a.y * di;
        float z0 = 0.f, z1 = 0.f;
#pragma unroll
        for (int j = 0; j < 16; j++) {
            float h = fmaf(a0, sW1[j], fmaf(a1, sW1[16 + j], sb1[j]));
            h = fmaxf(h, 0.f);
            z0 = fmaf(h, sW2[2 * j + 0], z0);
            z1 = fmaf(h, sW2[2 * j + 1], z1);
        }
        float2 s = make_float2(z0 * di, z1 * di);
        sz[i] = s;
        agg2[i] = s;
    }
}

__global__ void k_final(const float2* __restrict__ agg2, const float* __restrict__ dinv,
                        const float* __restrict__ b2, float2* __restrict__ out) {
    int i = blockIdx.x * blockDim.x + threadIdx.x;
    if (i < N) {
        float di = dinv[i];
        float2 a = agg2[i];
        float v0 = fmaf(a.x, di, b2[0]);
        float v1 = fmaf(a.y, di, b2[1]);
        float m = fmaxf(v0, v1);
        float lse = m + logf(expf(v0 - m) + expf(v1 - m));
        out[i] = make_float2(v0 - lse, v1 - lse);
    }
}

extern "C" void kernel_launch(void* const* d_in, const int* in_sizes, int n_in,
                              void* d_out, int out_size, void* d_ws, size_t ws_size,
                              hipStream_t stream) {
    const float* x  = (const float*)d_in[0];
    const int*   ei = (const int*)d_in[1];
    const float* W1 = (const float*)d_in[2];
    const float* b1 = (const float*)d_in[3];
    const float* W2 = (const float*)d_in[4];
    const float* b2 = (const float*)d_in[5];

    const int E = in_sizes[1] / 2;
    const int* src = ei;
    const int* dst = ei + E;

    // workspace layout (512B-aligned chunks)
    char* ws = (char*)d_ws;
    size_t off = 0;
    auto alloc = [&](size_t bytes) {
        char* p = ws + off;
        off += (bytes + 511) & ~size_t(511);
        return p;
    };
    int*    cnt  = (int*)alloc(N * sizeof(int));
    float*  dinv = (float*)alloc(N * sizeof(float));
    float2* sx   = (float2*)alloc(N * sizeof(float2));
    float2* agg1 = (float2*)alloc(N * sizeof(float2));
    float2* sz   = (float2*)alloc(N * sizeof(float2));
    float2* agg2 = (float2*)alloc(N * sizeof(float2));

    hipMemsetAsync(cnt, 0, N * sizeof(int), stream);

    const int BS = 256;
    const int gE = (E + BS - 1) / BS;
    const int gN = (N + BS - 1) / BS;

    k_deg<<<gE, BS, 0, stream>>>(dst, E, cnt);
    k_node1<<<gN, BS, 0, stream>>>(x, cnt, dinv, sx, agg1);
    k_scatter<<<gE, BS, 0, stream>>>(src, dst, E, sx, (float*)agg1);
    k_node2<<<gN, BS, 0, stream>>>(agg1, dinv, W1, b1, W2, sz, agg2);
    k_scatter<<<gE, BS, 0, stream>>>(src, dst, E, sz, (float*)agg2);
    k_final<<<gN, BS, 0, stream>>>(agg2, dinv, b2, (float2*)d_out);
}